// Round 1
// baseline (21.079 us; speedup 1.0000x reference)
//
#include <hip/hip_runtime.h>

// Problem constants (fixed by setup_inputs: N=4096, box=50, cutoff=5)
#define N_ATOMS 4096
#define CUTOFF_SQ 25.0f

// Each thread computes 4 consecutive output elements of one row and writes
// one float4. Threads-per-row = N/4 = 1024, so a 64-lane wave is entirely
// within one row -> the row-position load is a uniform broadcast.
__global__ __launch_bounds__(256) void pairdist_kernel(
    const float* __restrict__ q,      // [N,3] positions
    const float* __restrict__ cell,   // [3] box lengths
    float* __restrict__ out)          // [N,N] output
{
    const int tid = blockIdx.x * blockDim.x + threadIdx.x;  // 0 .. N*N/4-1
    const int row = tid >> 10;            // tid / (N/4)
    const int j0  = (tid & 1023) << 2;    // 4*(tid % (N/4))

    const float cx = cell[0], cy = cell[1], cz = cell[2];
    const float hx = 0.5f * cx, hy = 0.5f * cy, hz = 0.5f * cz;

    const float xi = q[3 * row + 0];
    const float yi = q[3 * row + 1];
    const float zi = q[3 * row + 2];

    float r[4];
#pragma unroll
    for (int k = 0; k < 4; ++k) {
        const int j = j0 + k;
        float dx = q[3 * j + 0] - xi;
        float dy = q[3 * j + 1] - yi;
        float dz = q[3 * j + 2] - zi;
        // minimum-image: offsets = (d < -c/2) - (d >= c/2); d += offsets*c
        dx += ((dx < -hx) ? cx : 0.0f) - ((dx >= hx) ? cx : 0.0f);
        dy += ((dy < -hy) ? cy : 0.0f) - ((dy >= hy) ? cy : 0.0f);
        dz += ((dz < -hz) ? cz : 0.0f) - ((dz >= hz) ? cz : 0.0f);
        const float d2 = dx * dx + dy * dy + dz * dz;
        const bool keep = (j >= row) & (d2 < CUTOFF_SQ) & (d2 != 0.0f);
        r[k] = keep ? d2 : 0.0f;
    }

    float4 res = make_float4(r[0], r[1], r[2], r[3]);
    *reinterpret_cast<float4*>(out + (size_t)tid * 4) = res;
}

extern "C" void kernel_launch(void* const* d_in, const int* in_sizes, int n_in,
                              void* d_out, int out_size, void* d_ws, size_t ws_size,
                              hipStream_t stream) {
    const float* q    = (const float*)d_in[0];
    const float* cell = (const float*)d_in[1];
    float* out = (float*)d_out;

    const int total_threads = (N_ATOMS * N_ATOMS) / 4;  // one float4 per thread
    const int block = 256;
    const int grid = total_threads / block;             // 16384 blocks
    pairdist_kernel<<<grid, block, 0, stream>>>(q, cell, out);
}

// Round 2
// 16.297 us; speedup vs baseline: 1.2934x; 1.2934x over previous
//
#include <hip/hip_runtime.h>

// Problem constants (fixed by setup_inputs: N=4096, box=50, cutoff=5)
#define N_ATOMS 4096
#define CUTOFF_SQ 25.0f

// Tile: each thread computes a 4x4 (rows x cols) block of the output.
// - 4 cols -> one float4 store per row (coalesced 1KB/wave stores)
// - 4 rows -> column xyz (48B) loaded once, reused 4x
// - i0 is block-uniform -> row positions become scalar (s_load) reads
// - tiles strictly below the diagonal store zeros with no loads/compute
__global__ __launch_bounds__(256) void pairdist_kernel(
    const float* __restrict__ q,      // [N,3] positions
    const float* __restrict__ cell,   // [3] box lengths
    float* __restrict__ out)          // [N,N] output
{
    const int rowgrp = blockIdx.x >> 2;                       // 0..1023
    const int i0 = rowgrp << 2;                               // first row (block-uniform)
    const int colt = ((blockIdx.x & 3) << 8) + threadIdx.x;   // 0..1023
    const int j0 = colt << 2;                                 // first col

    float* outp = out + (size_t)i0 * N_ATOMS + j0;

    // Entire 4x4 tile strictly below the diagonal -> zeros, no compute.
    // (i0, j0 are multiples of 4, so j0 < i0 implies j0+3 < i0.)
    if (j0 < i0) {
        const float4 z = make_float4(0.f, 0.f, 0.f, 0.f);
#pragma unroll
        for (int r = 0; r < 4; ++r)
            *reinterpret_cast<float4*>(outp + (size_t)r * N_ATOMS) = z;
        return;
    }

    const float cx = cell[0], cy = cell[1], cz = cell[2];

    // Row positions: block-uniform address -> scalar loads.
    const float* qi = q + 3 * i0;
    float xi[4], yi[4], zi[4];
#pragma unroll
    for (int r = 0; r < 4; ++r) {
        xi[r] = qi[3 * r + 0];
        yi[r] = qi[3 * r + 1];
        zi[r] = qi[3 * r + 2];
    }

    // Column positions: 48 contiguous bytes = 3 x float4 (16B-aligned).
    const float4* q4 = reinterpret_cast<const float4*>(q);
    const float4 a = q4[3 * colt + 0];
    const float4 b = q4[3 * colt + 1];
    const float4 c = q4[3 * colt + 2];
    const float xj[4] = {a.x, a.w, b.z, c.y};
    const float yj[4] = {a.y, b.x, b.w, c.z};
    const float zj[4] = {a.z, b.y, c.x, c.w};

#pragma unroll
    for (int r = 0; r < 4; ++r) {
        float res[4];
#pragma unroll
        for (int k = 0; k < 4; ++k) {
            // min-image |wrapped d| = min(|d|, c-|d|)  (bit-exact magnitude:
            // for the wrap cases |d +- c| == c - |d| in fp32)
            float dx = fabsf(xj[k] - xi[r]); dx = fminf(dx, cx - dx);
            float dy = fabsf(yj[k] - yi[r]); dy = fminf(dy, cy - dy);
            float dz = fabsf(zj[k] - zi[r]); dz = fminf(dz, cz - dz);
            const float d2 = dx * dx + dy * dy + dz * dz;
            const bool keep = (d2 < CUTOFF_SQ) & (d2 != 0.0f) &
                              ((j0 + k) >= (i0 + r));
            res[k] = keep ? d2 : 0.0f;
        }
        *reinterpret_cast<float4*>(outp + (size_t)r * N_ATOMS) =
            make_float4(res[0], res[1], res[2], res[3]);
    }
}

extern "C" void kernel_launch(void* const* d_in, const int* in_sizes, int n_in,
                              void* d_out, int out_size, void* d_ws, size_t ws_size,
                              hipStream_t stream) {
    const float* q    = (const float*)d_in[0];
    const float* cell = (const float*)d_in[1];
    float* out = (float*)d_out;

    // 1024 row-groups x 4 blocks/row-group (256 threads cover 1024 col-threads)
    const int grid = 4096;
    pairdist_kernel<<<grid, 256, 0, stream>>>(q, cell, out);
}